// Round 3
// baseline (509.124 us; speedup 1.0000x reference)
//
#include <hip/hip_runtime.h>

// Problem: D=4096, H=2 (head_dim 2048), E=8192, OUT=1, seq L=2, batch 1.
// Pure GEMV chain; roofline = 537 MB fp32 weights / ~6.3 TB/s ~= 85 us + launch overhead.
#define D4 4096
#define E8 8192

// Static device scratch (256 KB).
// Layout (fp32 elements): x[2*4096] @0 | qkv[2*12288] @8192 | o[2*4096] @32768
//                         | h[2*4096] @40960 | g[2*8192] @49152  (total 65536)
// Every element is written before it is read on every call (no stale state).
#define OFF_X    0
#define OFF_QKV  8192
#define OFF_O    32768
#define OFF_H    40960
#define OFF_G    49152
__device__ float g_ws[65536];

// x[0][i] = relu(ray0*w1[i]+b1[i]); x[1][i] = relu(ray1*w2[i]+b2[i])
__global__ void k_embed(const float* __restrict__ ray,
                        const float* __restrict__ w1,
                        const float* __restrict__ b1,
                        const float* __restrict__ w2,
                        const float* __restrict__ b2) {
    int i = blockIdx.x * blockDim.x + threadIdx.x;
    if (i < D4) {
        float r0 = ray[0], r1 = ray[1];
        g_ws[OFF_X + i]      = fmaxf(fmaf(r0, w1[i], b1[i]), 0.f);
        g_ws[OFF_X + D4 + i] = fmaxf(fmaf(r1, w2[i], b2[i]), 0.f);
    }
}

// Generic 2-token GEMV: out[l*R+row] = act( dot(W[row,:], xin[l,:]) + bias[row] (+ resid) )
// 512 threads = 8 waves = 8 rows per block. x (both tokens, 32 KB) is staged in LDS
// once per block so the steady-state inner loop is exactly ONE global float4 (weight)
// + 2 ds_read_b128 per iteration. Unroll bounded at 4 -> small live set, no spills.
// __launch_bounds__(512,4): cap 128 VGPR -> >=2 blocks/CU (16 waves), LDS 32KB/block.
__global__ __launch_bounds__(512, 4) void k_gemv2(
        const float* __restrict__ W,
        const float* __restrict__ bias,
        int xin_off, int out_off, int resid_off,
        int R, int relu_flag) {
    __shared__ float sx[2 * D4];                     // 32 KB
    const float* xin = g_ws + xin_off;
    int tid = threadIdx.x;
    #pragma unroll
    for (int it = 0; it < (2 * D4) / (512 * 4); ++it) {   // 4 coalesced float4 passes
        int j = (it * 512 + tid) * 4;
        *(float4*)(sx + j) = *(const float4*)(xin + j);
    }
    __syncthreads();

    int row  = blockIdx.x * 8 + (tid >> 6);
    int lane = tid & 63;
    const float* wrow = W + (size_t)row * D4;
    float acc0 = 0.f, acc1 = 0.f;
    #pragma unroll 4
    for (int it = 0; it < D4 / (64 * 4); ++it) {     // 16 iterations
        int j = (it * 64 + lane) * 4;                // coalesced 16B/lane
        float4 wv = *(const float4*)(wrow + j);
        float4 x0 = *(const float4*)(sx + j);
        float4 x1 = *(const float4*)(sx + D4 + j);
        acc0 = fmaf(wv.x, x0.x, fmaf(wv.y, x0.y, fmaf(wv.z, x0.z, fmaf(wv.w, x0.w, acc0))));
        acc1 = fmaf(wv.x, x1.x, fmaf(wv.y, x1.y, fmaf(wv.z, x1.z, fmaf(wv.w, x1.w, acc1))));
    }
    #pragma unroll
    for (int off = 32; off; off >>= 1) {
        acc0 += __shfl_down(acc0, off);
        acc1 += __shfl_down(acc1, off);
    }
    if (lane == 0) {
        float b  = bias[row];
        float r0 = acc0 + b, r1 = acc1 + b;
        if (resid_off >= 0) {
            r0 += g_ws[resid_off + row];
            r1 += g_ws[resid_off + R + row];
        }
        if (relu_flag) { r0 = fmaxf(r0, 0.f); r1 = fmaxf(r1, 0.f); }
        g_ws[out_off + row]     = r0;
        g_ws[out_off + R + row] = r1;
    }
}

// Tiny MHA core: qkv fp32 [2, 3*4096] -> o fp32 [2, 4096]. H=2, head_dim=2048, S=2.
// 1024 threads (16 waves) on one CU to cut the latency-bound tail.
// acc kept as named scalars (no runtime-indexed per-thread array -> no scratch).
__global__ void k_attn() {
    const int HD = D4 / 2;  // 2048
    const float* qkv = g_ws + OFF_QKV;
    float* o = g_ws + OFF_O;
    __shared__ float sred[8][16];
    __shared__ float sattn[2][2][2];  // [h][l][m]
    int tid = threadIdx.x, lane = tid & 63, wave = tid >> 6;

    float a000 = 0.f, a001 = 0.f, a010 = 0.f, a011 = 0.f;  // h=0
    float a100 = 0.f, a101 = 0.f, a110 = 0.f, a111 = 0.f;  // h=1
    #pragma unroll
    for (int it = 0; it < 2; ++it) {                 // i in [0, 2048): h = 0
        int i = it * 1024 + tid;
        float q0 = qkv[0 * 3 * D4 + i];
        float q1 = qkv[1 * 3 * D4 + i];
        float k0 = qkv[0 * 3 * D4 + D4 + i];
        float k1 = qkv[1 * 3 * D4 + D4 + i];
        a000 += q0 * k0; a001 += q0 * k1;
        a010 += q1 * k0; a011 += q1 * k1;
    }
    #pragma unroll
    for (int it = 0; it < 2; ++it) {                 // i in [2048, 4096): h = 1
        int i = HD + it * 1024 + tid;
        float q0 = qkv[0 * 3 * D4 + i];
        float q1 = qkv[1 * 3 * D4 + i];
        float k0 = qkv[0 * 3 * D4 + D4 + i];
        float k1 = qkv[1 * 3 * D4 + D4 + i];
        a100 += q0 * k0; a101 += q0 * k1;
        a110 += q1 * k0; a111 += q1 * k1;
    }
    #define WREDUCE(v, idx) { float t_ = (v); \
        _Pragma("unroll") \
        for (int off_ = 32; off_; off_ >>= 1) t_ += __shfl_down(t_, off_); \
        if (lane == 0) sred[idx][wave] = t_; }
    WREDUCE(a000, 0) WREDUCE(a001, 1) WREDUCE(a010, 2) WREDUCE(a011, 3)
    WREDUCE(a100, 4) WREDUCE(a101, 5) WREDUCE(a110, 6) WREDUCE(a111, 7)
    #undef WREDUCE
    __syncthreads();
    if (tid == 0) {
        float scale = rsqrtf((float)HD);
        for (int h = 0; h < 2; h++)
            for (int l = 0; l < 2; l++) {
                float s0 = 0.f, s1 = 0.f;
                for (int w = 0; w < 16; w++) {
                    s0 += sred[(h * 2 + l) * 2 + 0][w];
                    s1 += sred[(h * 2 + l) * 2 + 1][w];
                }
                s0 *= scale; s1 *= scale;
                float mx = fmaxf(s0, s1);
                float e0 = __expf(s0 - mx), e1 = __expf(s1 - mx);
                float inv = 1.f / (e0 + e1);
                sattn[h][l][0] = e0 * inv;
                sattn[h][l][1] = e1 * inv;
            }
    }
    __syncthreads();
    #pragma unroll
    for (int it = 0; it < 4; ++it) {
        int i = it * 1024 + tid;
        int h = i >> 11;                             // i / 2048
        float v0 = qkv[0 * 3 * D4 + 2 * D4 + i];
        float v1 = qkv[1 * 3 * D4 + 2 * D4 + i];
        o[i]      = sattn[h][0][0] * v0 + sattn[h][0][1] * v1;
        o[D4 + i] = sattn[h][1][0] * v0 + sattn[h][1][1] * v1;
    }
}

// Final: y[l] = dot(w2, g[l]) + b2; out = fp32 mean over l. 1024 threads.
__global__ void k_expert_out(const float* __restrict__ w2,
                             const float* __restrict__ b2,
                             float* __restrict__ out) {
    const float* g = g_ws + OFF_G;
    __shared__ float sred[2][16];
    int tid = threadIdx.x, lane = tid & 63, wave = tid >> 6;
    float a0 = 0.f, a1 = 0.f;
    #pragma unroll
    for (int it = 0; it < E8 / 1024; ++it) {         // 8 iterations
        int e = it * 1024 + tid;
        float w = w2[e];
        a0 += w * g[e];
        a1 += w * g[E8 + e];
    }
    #pragma unroll
    for (int off = 32; off; off >>= 1) {
        a0 += __shfl_down(a0, off);
        a1 += __shfl_down(a1, off);
    }
    if (lane == 0) { sred[0][wave] = a0; sred[1][wave] = a1; }
    __syncthreads();
    if (tid == 0) {
        float b = b2[0];
        float y0 = b, y1 = b;
        for (int w = 0; w < 16; w++) { y0 += sred[0][w]; y1 += sred[1][w]; }
        out[0] = 0.5f * (y0 + y1);
    }
}

extern "C" void kernel_launch(void* const* d_in, const int* in_sizes, int n_in,
                              void* d_out, int out_size, void* d_ws, size_t ws_size,
                              hipStream_t stream) {
    const float* ray        = (const float*)d_in[0];
    const float* emb1_w     = (const float*)d_in[1];
    const float* emb1_b     = (const float*)d_in[2];
    const float* emb2_w     = (const float*)d_in[3];
    const float* emb2_b     = (const float*)d_in[4];
    const float* attn_in_w  = (const float*)d_in[5];
    const float* attn_in_b  = (const float*)d_in[6];
    const float* attn_out_w = (const float*)d_in[7];
    const float* attn_out_b = (const float*)d_in[8];
    const float* ffn1_w     = (const float*)d_in[9];
    const float* ffn1_b     = (const float*)d_in[10];
    const float* ffn2_w     = (const float*)d_in[11];
    const float* ffn2_b     = (const float*)d_in[12];
    const float* exp_w1     = (const float*)d_in[13];
    const float* exp_b1     = (const float*)d_in[14];
    const float* exp_w2     = (const float*)d_in[15];
    const float* exp_b2     = (const float*)d_in[16];
    float* out = (float*)d_out;
    (void)d_ws; (void)ws_size; (void)in_sizes; (void)n_in;  // idx = d_in[17] unused (n_experts=1)

    k_embed<<<(D4 + 255) / 256, 256, 0, stream>>>(ray, emb1_w, emb1_b, emb2_w, emb2_b);
    // qkv = x @ attn_in_w.T + b   [2, 12288]
    k_gemv2<<<3 * D4 / 8, 512, 0, stream>>>(attn_in_w, attn_in_b, OFF_X, OFF_QKV, -1, 3 * D4, 0);
    k_attn<<<1, 1024, 0, stream>>>();
    // x += o @ attn_out_w.T + b
    k_gemv2<<<D4 / 8, 512, 0, stream>>>(attn_out_w, attn_out_b, OFF_O, OFF_X, OFF_X, D4, 0);
    // h = relu(x @ ffn1_w.T + b)
    k_gemv2<<<D4 / 8, 512, 0, stream>>>(ffn1_w, ffn1_b, OFF_X, OFF_H, -1, D4, 1);
    // x += h @ ffn2_w.T + b
    k_gemv2<<<D4 / 8, 512, 0, stream>>>(ffn2_w, ffn2_b, OFF_H, OFF_X, OFF_X, D4, 0);
    // g = relu(x @ exp_w1.T + b1)   [2, 8192]
    k_gemv2<<<E8 / 8, 512, 0, stream>>>(exp_w1, exp_b1, OFF_X, OFF_G, -1, E8, 1);
    // out = mean_l(dot(exp_w2, g[l]) + b2)
    k_expert_out<<<1, 1024, 0, stream>>>(exp_w2, exp_b2, out);
}